// Round 2
// baseline (253.675 us; speedup 1.0000x reference)
//
#include <hip/hip_runtime.h>

// Shapes: msa [1,128,256,256] f32, pair [1,256,256,128] f32, out same as pair.
// ws: leftT [256 l][32 i][128 s] bf16 (pre-XOR-swizzled, 2MB) | rightT same (2MB)
//     | w2 [16 ck][128 p][64 kc] bf16, k' = jj*32+ii permuted (256KB)
//     | wTg [64 c][256 d] bf16 (32KB)

typedef float v4f __attribute__((ext_vector_type(4)));
typedef short v8s __attribute__((ext_vector_type(8)));

static __device__ inline unsigned short f2bf(float x) {
    unsigned int u = __builtin_bit_cast(unsigned int, x);
    return (unsigned short)((u + 0x7fffu + ((u >> 16) & 1u)) >> 16);
}

// ---------------- one-time weight reformat ----------------
// blocks 0..63: w2 (permuted k' = jj*32+ii); blocks 64..71: wTg [c][d]
__global__ __launch_bounds__(256) void k_prep(const float* __restrict__ w_out,
                                              const float* __restrict__ wl,
                                              const float* __restrict__ wr,
                                              unsigned short* __restrict__ w2,
                                              unsigned short* __restrict__ wTg) {
    const int b = blockIdx.x, t = threadIdx.x;
    unsigned short tmp[8];
    if (b < 64) {
        int tgt = b * 2048 + t * 8;            // linear = ck*8192 + p*64 + kc
        int ck = tgt >> 13;
        int rem = tgt & 8191;
        int p = rem >> 6, kc0 = rem & 63;
        for (int e = 0; e < 8; ++e) {
            int kp = ck * 64 + kc0 + e;        // k' = jj*32 + ii
            int jj = kp >> 5, ii = kp & 31;
            tmp[e] = f2bf(w_out[(ii * 32 + jj) * 128 + p]);
        }
        *(uint4*)&w2[tgt] = *(const uint4*)tmp;
    } else {
        int tgt = (b - 64) * 2048 + t * 8;     // linear = c*256 + d
        int c = tgt >> 8, d0 = tgt & 255;
        const float* src = (c < 32) ? wl : wr;
        int cc = c & 31;
        for (int e = 0; e < 8; ++e) tmp[e] = f2bf(src[(d0 + e) * 32 + cc]);
        *(uint4*)&wTg[tgt] = *(const uint4*)tmp;
    }
}

// ---------------- LayerNorm + left/right projection ----------------
// grid (256 l, 4 s-quarters), block 256. W fragments straight from global (L2-hot).
__global__ __launch_bounds__(256) void k_lnproj(
    const float* __restrict__ msa, const float* __restrict__ gamma, const float* __restrict__ beta,
    const unsigned short* __restrict__ wTg, const float* __restrict__ bl, const float* __restrict__ br,
    unsigned short* __restrict__ leftT, unsigned short* __restrict__ rightT) {
    __shared__ unsigned short xb[32 * 264];    // [32 s][256 d + 8 pad] bf16
    __shared__ unsigned short outT[64 * 40];   // [64 c][32 s + 8 pad] bf16

    const int t = threadIdx.x, lane = t & 63, w = t >> 6;
    const int l = blockIdx.x, s0 = blockIdx.y * 32;
    const int quad = lane >> 4, l15 = lane & 15;

    // LayerNorm: each wave does 8 rows of 256
    float4 g4 = *(const float4*)&gamma[lane * 4];
    float4 be4 = *(const float4*)&beta[lane * 4];
    for (int r = 0; r < 8; ++r) {
        int sl = w * 8 + r;
        const float* row = msa + (size_t)((s0 + sl) * 256 + l) * 256;
        float4 v = *(const float4*)&row[lane * 4];
        float sum = v.x + v.y + v.z + v.w;
        float sq = v.x * v.x + v.y * v.y + v.z * v.z + v.w * v.w;
        for (int o = 32; o > 0; o >>= 1) { sum += __shfl_xor(sum, o); sq += __shfl_xor(sq, o); }
        float mu = sum * (1.f / 256);
        float rs = rsqrtf(sq * (1.f / 256) - mu * mu + 1e-5f);
        ushort4 xs;
        xs.x = f2bf((v.x - mu) * rs * g4.x + be4.x);
        xs.y = f2bf((v.y - mu) * rs * g4.y + be4.y);
        xs.z = f2bf((v.z - mu) * rs * g4.z + be4.z);
        xs.w = f2bf((v.w - mu) * rs * g4.w + be4.w);
        *(ushort4*)&xb[sl * 264 + lane * 4] = xs;
    }
    __syncthreads();

    // MFMA: M=32 (s), N=64 (c), K=256. wave w: M-tile w>>1, N-tiles (w&1)*2 + {0,1}
    const int mt = w >> 1, ntb = (w & 1) * 2;
    v4f acc[2] = {};
    const int frow = (mt * 16 + l15) * 264;
    for (int ks = 0; ks < 8; ++ks) {
        int k = ks * 32 + quad * 8;
        v8s a = *(const v8s*)&xb[frow + k];
        v8s b0 = *(const v8s*)&wTg[(ntb * 16 + l15) * 256 + k];
        v8s b1 = *(const v8s*)&wTg[((ntb + 1) * 16 + l15) * 256 + k];
        acc[0] = __builtin_amdgcn_mfma_f32_16x16x32_bf16(a, b0, acc[0], 0, 0, 0);
        acc[1] = __builtin_amdgcn_mfma_f32_16x16x32_bf16(a, b1, acc[1], 0, 0, 0);
    }

    // epilogue: bias (+ 1/N scale for right), bf16, transpose via LDS
    for (int tn = 0; tn < 2; ++tn) {
        int c = (ntb + tn) * 16 + l15;
        float bias = c < 32 ? bl[c] : br[c - 32];
        float scale = c < 32 ? 1.f : (1.f / 128);
        for (int r = 0; r < 4; ++r) {
            int sl = mt * 16 + quad * 4 + r;
            outT[c * 40 + sl] = f2bf((acc[tn][r] + bias) * scale);
        }
    }
    __syncthreads();

    // 16B global writes, PRE-SWIZZLED: within each 64-s half, 8-short group g
    // stored at g ^ (i&7) so k_outer's LDS image is XOR-swizzled after linear copy.
    {
        int c = t >> 2, q = t & 3;
        uint4 vv = *(const uint4*)&outT[c * 40 + q * 8];
        int kh = s0 >> 6;
        int g = ((s0 & 32) >> 3) + q;          // 0..7 within the 64-s half
        int g2 = g ^ (c & 7);                  // (c-32)&7 == c&7
        unsigned short* dst = (c < 32) ? (leftT + l * 4096 + c * 128)
                                       : (rightT + l * 4096 + (c - 32) * 128);
        *(uint4*)&dst[kh * 64 + g2 * 8] = vv;
    }
}

// ---------------- fused outer-product + w_out projection ----------------
// grid (64,64): 4x4 (l,m) tile per block, 256 threads (4 waves, 2x2).
__global__ __launch_bounds__(256, 4) void k_outer(
    const unsigned short* __restrict__ leftT, const unsigned short* __restrict__ rightT,
    const unsigned short* __restrict__ w2, const float* __restrict__ bout,
    const float* __restrict__ pairIn, float* __restrict__ out) {
    __shared__ alignas(16) unsigned short smem[16 * 1024];   // 32 KB
    unsigned short* Ah = smem;           // [128][64] phase A (swizzled content)
    unsigned short* Bh = smem + 8192;    // [128][64] phase A
    unsigned short* Obuf = smem;         // [16][1024] phase B, XOR-swizzled by row&7

    const int t = threadIdx.x, lane = t & 63, w = t >> 6;
    const int l0 = blockIdx.x * 4, m0 = blockIdx.y * 4;
    const int wm = w & 1, wn = w >> 1;
    const int quad = lane >> 4, l15 = lane & 15;

    const unsigned short* Asrc = leftT + l0 * 4096;    // [4 l][32 i][128 s]
    const unsigned short* Bsrc = rightT + m0 * 4096;

    // ---- phase A: O[128x128] = A·B^T over K=s=128, in 2 halves of 64
    v4f acc[4][4] = {};
    for (int kh = 0; kh < 2; ++kh) {
        __syncthreads();
        for (int it = 0; it < 4; ++it) {
            int el = (it * 256 + t) * 8;
            int m = el >> 6, off = el & 63;
            *(uint4*)&Ah[m * 64 + off] = *(const uint4*)&Asrc[m * 128 + kh * 64 + off];
            *(uint4*)&Bh[m * 64 + off] = *(const uint4*)&Bsrc[m * 128 + kh * 64 + off];
        }
        __syncthreads();
        for (int ks = 0; ks < 2; ++ks) {
            int g = ks * 4 + quad;                     // 8-short group within half
            v8s a[4], bb[4];
            for (int i = 0; i < 4; ++i) {
                int row = wm * 64 + i * 16 + l15;
                a[i] = *(const v8s*)&Ah[row * 64 + ((g ^ (l15 & 7)) << 3)];
            }
            for (int j = 0; j < 4; ++j) {
                int row = wn * 64 + j * 16 + l15;
                bb[j] = *(const v8s*)&Bh[row * 64 + ((g ^ (l15 & 7)) << 3)];
            }
            for (int i = 0; i < 4; ++i)
                for (int j = 0; j < 4; ++j)
                    acc[i][j] = __builtin_amdgcn_mfma_f32_16x16x32_bf16(a[i], bb[j], acc[i][j], 0, 0, 0);
        }
    }
    __syncthreads();   // phase-A reads done before Obuf overwrites Ah/Bh

    // ---- scatter acc -> Obuf[pair][k'=jj*32+ii], b64 writes, XOR by pair&7
    for (int i = 0; i < 4; ++i)
        for (int j = 0; j < 4; ++j) {
            int pr = (wm * 2 + (i >> 1)) * 4 + (wn * 2 + (j >> 1));
            int jj = (j & 1) * 16 + l15;
            int gw = jj * 4 + (i & 1) * 2 + (quad >> 1);
            int addr = pr * 1024 + ((gw ^ (pr & 7)) << 3) + (quad & 1) * 4;
            ushort4 v;
            v.x = f2bf(acc[i][j][0]); v.y = f2bf(acc[i][j][1]);
            v.z = f2bf(acc[i][j][2]); v.w = f2bf(acc[i][j][3]);
            *(ushort4*)&Obuf[addr] = v;
        }
    __syncthreads();

    // ---- phase B: P[16][128] = Obuf[16][1024] @ W2 — B-frags straight from global
    v4f acc2[2] = {};
    for (int ck = 0; ck < 16; ++ck) {
        for (int inner = 0; inner < 2; ++inner) {
            int g = ck * 8 + inner * 4 + quad;
            v8s a = *(const v8s*)&Obuf[l15 * 1024 + (((g ^ (l15 & 7)) & 7) << 3) + ((g >> 3) << 6)];
            for (int tt = 0; tt < 2; ++tt) {
                int p = (w * 2 + tt) * 16 + l15;
                v8s bfr = *(const v8s*)&w2[ck * 8192 + p * 64 + inner * 32 + quad * 8];
                acc2[tt] = __builtin_amdgcn_mfma_f32_16x16x32_bf16(a, bfr, acc2[tt], 0, 0, 0);
            }
        }
    }

    // ---- epilogue: out = pair + P + b_out
    for (int tt = 0; tt < 2; ++tt) {
        int p = (w * 2 + tt) * 16 + l15;
        float bo = bout[p];
        for (int r = 0; r < 4; ++r) {
            int pr = quad * 4 + r;
            int dl = pr >> 2, dm = pr & 3;
            size_t idx = (size_t)((l0 + dl) * 256 + (m0 + dm)) * 128 + p;
            out[idx] = pairIn[idx] + bo + acc2[tt][r];
        }
    }
}

extern "C" void kernel_launch(void* const* d_in, const int* in_sizes, int n_in,
                              void* d_out, int out_size, void* d_ws, size_t ws_size,
                              hipStream_t stream) {
    const float* msa   = (const float*)d_in[0];
    const float* pairI = (const float*)d_in[1];
    const float* gamma = (const float*)d_in[4];
    const float* beta  = (const float*)d_in[5];
    const float* wl    = (const float*)d_in[6];
    const float* bl    = (const float*)d_in[7];
    const float* wr    = (const float*)d_in[8];
    const float* br    = (const float*)d_in[9];
    const float* wout  = (const float*)d_in[10];
    const float* bout  = (const float*)d_in[11];
    float* out = (float*)d_out;

    unsigned short* leftT  = (unsigned short*)d_ws;       // 1,048,576 el
    unsigned short* rightT = leftT + 256 * 32 * 128;      // 1,048,576 el
    unsigned short* w2     = rightT + 256 * 32 * 128;     // 131,072 el
    unsigned short* wTg    = w2 + 131072;                 // 16,384 el

    k_prep<<<dim3(72), 256, 0, stream>>>(wout, wl, wr, w2, wTg);
    k_lnproj<<<dim3(256, 4), 256, 0, stream>>>(msa, gamma, beta, wTg, bl, br, leftT, rightT);
    k_outer<<<dim3(64, 64), 256, 0, stream>>>(leftT, rightT, w2, bout, pairI, out);
}

// Round 3
// 200.699 us; speedup vs baseline: 1.2640x; 1.2640x over previous
//
#include <hip/hip_runtime.h>

// Shapes: msa [1,128,256,256] f32, pair [1,256,256,128] f32, out same as pair.
// ws: leftT [256 l][32 i][128 s] bf16 (pre-XOR-swizzled) | rightT same
//     | w2 [16 ck][128 p][64 kc] bf16 with k' = j1*512+quad*128+l15*8+i1*4+r
//     | wTg [64 c][256 d] bf16

typedef float v4f __attribute__((ext_vector_type(4)));
typedef short v8s __attribute__((ext_vector_type(8)));

static __device__ inline unsigned short f2bf(float x) {
    unsigned int u = __builtin_bit_cast(unsigned int, x);
    return (unsigned short)((u + 0x7fffu + ((u >> 16) & 1u)) >> 16);
}

// ---------------- one-time weight reformat ----------------
// blocks 0..63: w2 (k' permuted); blocks 64..71: wTg [c][d]
__global__ __launch_bounds__(256) void k_prep(const float* __restrict__ w_out,
                                              const float* __restrict__ wl,
                                              const float* __restrict__ wr,
                                              unsigned short* __restrict__ w2,
                                              unsigned short* __restrict__ wTg) {
    const int b = blockIdx.x, t = threadIdx.x;
    unsigned short tmp[8];
    if (b < 64) {
        int tgt = b * 2048 + t * 8;            // linear = ck*8192 + p*64 + kc
        int p = (tgt >> 6) & 127;
        int ck = tgt >> 13, kc0 = tgt & 63;
        for (int e = 0; e < 8; ++e) {
            int kp = ck * 64 + kc0 + e;        // k' (10 bits)
            int j1 = (kp >> 9) & 1, qd = (kp >> 7) & 3, lp = (kp >> 3) & 15;
            int i1 = (kp >> 2) & 1, r = kp & 3;
            int ii = i1 * 16 + qd * 4 + r, jj = j1 * 16 + lp;
            tmp[e] = f2bf(w_out[(ii * 32 + jj) * 128 + p]);
        }
        *(uint4*)&w2[tgt] = *(const uint4*)tmp;
    } else {
        int tgt = (b - 64) * 2048 + t * 8;     // linear = c*256 + d
        int c = tgt >> 8, d0 = tgt & 255;
        const float* src = (c < 32) ? wl : wr;
        int cc = c & 31;
        for (int e = 0; e < 8; ++e) tmp[e] = f2bf(src[(d0 + e) * 32 + cc]);
        *(uint4*)&wTg[tgt] = *(const uint4*)tmp;
    }
}

// ---------------- LayerNorm + left/right projection ----------------
// grid (256 l, 4 s-quarters), block 256.
__global__ __launch_bounds__(256) void k_lnproj(
    const float* __restrict__ msa, const float* __restrict__ gamma, const float* __restrict__ beta,
    const unsigned short* __restrict__ wTg, const float* __restrict__ bl, const float* __restrict__ br,
    unsigned short* __restrict__ leftT, unsigned short* __restrict__ rightT) {
    __shared__ unsigned short xb[32 * 264];     // [32 s][256 d + 8 pad]
    __shared__ unsigned short wlds[64 * 264];   // [64 c][256 d + 8 pad]
    __shared__ unsigned short outT[64 * 40];    // [64 c][32 s + 8 pad]

    const int t = threadIdx.x, lane = t & 63, w = t >> 6;
    const int l = blockIdx.x, s0 = blockIdx.y * 32;
    const int quad = lane >> 4, l15 = lane & 15;

    // stage W: coalesced b128, padded rows (min-conflict writes)
    for (int it = 0; it < 8; ++it) {
        int idx = it * 2048 + t * 8;
        *(uint4*)&wlds[(idx >> 8) * 264 + (idx & 255)] = *(const uint4*)&wTg[idx];
    }

    // LayerNorm: wave does 8 rows, reduction batched for 8-way ILP
    float4 g4 = *(const float4*)&gamma[lane * 4];
    float4 be4 = *(const float4*)&beta[lane * 4];
    float4 vr[8]; float s1[8], s2[8];
    for (int r = 0; r < 8; ++r) {
        const float* row = msa + (size_t)((s0 + w * 8 + r) * 256 + l) * 256;
        vr[r] = *(const float4*)&row[lane * 4];
    }
    for (int r = 0; r < 8; ++r) {
        float4 v = vr[r];
        s1[r] = v.x + v.y + v.z + v.w;
        s2[r] = v.x * v.x + v.y * v.y + v.z * v.z + v.w * v.w;
    }
    for (int o = 32; o > 0; o >>= 1)
        for (int r = 0; r < 8; ++r) { s1[r] += __shfl_xor(s1[r], o); s2[r] += __shfl_xor(s2[r], o); }
    for (int r = 0; r < 8; ++r) {
        float mu = s1[r] * (1.f / 256);
        float rs = rsqrtf(s2[r] * (1.f / 256) - mu * mu + 1e-5f);
        float4 v = vr[r];
        ushort4 xs;
        xs.x = f2bf((v.x - mu) * rs * g4.x + be4.x);
        xs.y = f2bf((v.y - mu) * rs * g4.y + be4.y);
        xs.z = f2bf((v.z - mu) * rs * g4.z + be4.z);
        xs.w = f2bf((v.w - mu) * rs * g4.w + be4.w);
        *(ushort4*)&xb[(w * 8 + r) * 264 + lane * 4] = xs;
    }
    __syncthreads();

    // MFMA: M=32 (s), N=64 (c), K=256
    const int mt = w >> 1, ntb = (w & 1) * 2;
    v4f acc[2] = {};
    const int frow = (mt * 16 + l15) * 264;
    for (int ks = 0; ks < 8; ++ks) {
        int k = ks * 32 + quad * 8;
        v8s a = *(const v8s*)&xb[frow + k];
        v8s b0 = *(const v8s*)&wlds[(ntb * 16 + l15) * 264 + k];
        v8s b1 = *(const v8s*)&wlds[((ntb + 1) * 16 + l15) * 264 + k];
        acc[0] = __builtin_amdgcn_mfma_f32_16x16x32_bf16(a, b0, acc[0], 0, 0, 0);
        acc[1] = __builtin_amdgcn_mfma_f32_16x16x32_bf16(a, b1, acc[1], 0, 0, 0);
    }

    for (int tn = 0; tn < 2; ++tn) {
        int c = (ntb + tn) * 16 + l15;
        float bias = c < 32 ? bl[c] : br[c - 32];
        float scale = c < 32 ? 1.f : (1.f / 128);
        for (int r = 0; r < 4; ++r)
            outT[c * 40 + mt * 16 + quad * 4 + r] = f2bf((acc[tn][r] + bias) * scale);
    }
    __syncthreads();

    // pre-swizzled 16B global writes (k_outer's linear copy lands XOR-swizzled)
    {
        int c = t >> 2, q = t & 3;
        uint4 vv = *(const uint4*)&outT[c * 40 + q * 8];
        int kh = s0 >> 6;
        int g = ((s0 & 32) >> 3) + q;
        int g2 = g ^ (c & 7);
        unsigned short* dst = (c < 32) ? (leftT + l * 4096 + c * 128)
                                       : (rightT + l * 4096 + (c - 32) * 128);
        *(uint4*)&dst[kh * 64 + g2 * 8] = vv;
    }
}

// ---------------- fused outer-product + w_out projection ----------------
// grid (64,64): 4x4 (l,m) tile, 256 threads (4 waves, 2x2). LDS 48 KB.
__global__ __launch_bounds__(256) void k_outer(
    const unsigned short* __restrict__ leftT, const unsigned short* __restrict__ rightT,
    const unsigned short* __restrict__ w2g, const float* __restrict__ bout,
    const float* __restrict__ pairIn, float* __restrict__ out) {
    __shared__ alignas(16) unsigned short smem[24576];   // 48 KB
    unsigned short* Ah = smem;            // [128][64] phase A (swizzled content)
    unsigned short* Bh = smem + 8192;
    unsigned short* Obuf = smem;          // [16][1024] phase B, group-XOR by row&7
    unsigned short* wbuf = smem + 16384;  // 4 x wave-private [32 p][64 kc] (4 KB each)

    const int t = threadIdx.x, lane = t & 63, w = t >> 6;
    const int l0 = blockIdx.x * 4, m0 = blockIdx.y * 4;
    const int wm = w & 1, wn = w >> 1;
    const int quad = lane >> 4, l15 = lane & 15;

    const unsigned short* Asrc = leftT + l0 * 4096;
    const unsigned short* Bsrc = rightT + m0 * 4096;

    // ---- phase A: O[128x128] = A·B^T over K=s=128, 2 halves of 64
    v4f acc[4][4] = {};
    for (int kh = 0; kh < 2; ++kh) {
        __syncthreads();
        for (int it = 0; it < 4; ++it) {
            int el = (it * 256 + t) * 8;
            int m = el >> 6, off = el & 63;
            *(uint4*)&Ah[m * 64 + off] = *(const uint4*)&Asrc[m * 128 + kh * 64 + off];
            *(uint4*)&Bh[m * 64 + off] = *(const uint4*)&Bsrc[m * 128 + kh * 64 + off];
        }
        __syncthreads();
        for (int ks = 0; ks < 2; ++ks) {
            int g = ks * 4 + quad;
            v8s a[4], bb[4];
            for (int i = 0; i < 4; ++i)
                a[i] = *(const v8s*)&Ah[(wm * 64 + i * 16 + l15) * 64 + ((g ^ (l15 & 7)) << 3)];
            for (int j = 0; j < 4; ++j)
                bb[j] = *(const v8s*)&Bh[(wn * 64 + j * 16 + l15) * 64 + ((g ^ (l15 & 7)) << 3)];
            for (int i = 0; i < 4; ++i)
                for (int j = 0; j < 4; ++j)
                    acc[i][j] = __builtin_amdgcn_mfma_f32_16x16x32_bf16(a[i], bb[j], acc[i][j], 0, 0, 0);
        }
    }
    __syncthreads();   // phase-A LDS reads done before Obuf overwrite

    // ---- scatter acc -> Obuf, k' = j1*512+quad*128+l15*8+i1*4+r, 16B/lane contiguous
    for (int a2 = 0; a2 < 2; ++a2)
        for (int b2 = 0; b2 < 2; ++b2) {
            int pr = (wm * 2 + a2) * 4 + wn * 2 + b2;
            for (int j1 = 0; j1 < 2; ++j1) {
                unsigned short tmp8[8];
                for (int i1 = 0; i1 < 2; ++i1)
                    for (int r = 0; r < 4; ++r)
                        tmp8[i1 * 4 + r] = f2bf(acc[a2 * 2 + i1][b2 * 2 + j1][r]);
                int pg = (j1 * 64 + lane) ^ (pr & 7);
                *(uint4*)&Obuf[pr * 1024 + pg * 8] = *(const uint4*)tmp8;
            }
        }
    __syncthreads();

    // ---- phase B: P[16][128] = Obuf @ W2 — wave-private LDS staging, no barriers
    v4f acc2[2] = {};
    {
        const unsigned short* wsrc = w2g + w * 2048;   // wave's 32-p slice of each ck chunk
        unsigned short* wb = wbuf + w * 2048;
        int wa[4];
        uint4 pf[4];
        for (int u = 0; u < 4; ++u) {
            int g2 = (lane & 1) * 4 + u;
            wa[u] = (lane >> 1) * 64 + ((g2 ^ ((lane >> 1) & 7)) << 3);
            pf[u] = *(const uint4*)&wsrc[lane * 32 + u * 8];
        }
        for (int ck = 0; ck < 16; ++ck) {
            for (int u = 0; u < 4; ++u) *(uint4*)&wb[wa[u]] = pf[u];
            if (ck < 15)
                for (int u = 0; u < 4; ++u)
                    pf[u] = *(const uint4*)&wsrc[(ck + 1) * 8192 + lane * 32 + u * 8];
            for (int inner = 0; inner < 2; ++inner) {
                int g = ck * 8 + inner * 4 + quad;
                v8s a = *(const v8s*)&Obuf[l15 * 1024 + ((g ^ (l15 & 7)) << 3)];
                for (int tt = 0; tt < 2; ++tt) {
                    v8s bfr = *(const v8s*)&wb[(tt * 16 + l15) * 64 + (((inner * 4 + quad) ^ (l15 & 7)) << 3)];
                    acc2[tt] = __builtin_amdgcn_mfma_f32_16x16x32_bf16(a, bfr, acc2[tt], 0, 0, 0);
                }
            }
        }
    }

    // ---- epilogue: out = pair + P + b_out
    for (int tt = 0; tt < 2; ++tt) {
        int p = (w * 2 + tt) * 16 + l15;
        float bo = bout[p];
        for (int r = 0; r < 4; ++r) {
            int pr = quad * 4 + r;
            int dl = pr >> 2, dm = pr & 3;
            size_t idx = (size_t)((l0 + dl) * 256 + (m0 + dm)) * 128 + p;
            out[idx] = pairIn[idx] + bo + acc2[tt][r];
        }
    }
}

extern "C" void kernel_launch(void* const* d_in, const int* in_sizes, int n_in,
                              void* d_out, int out_size, void* d_ws, size_t ws_size,
                              hipStream_t stream) {
    const float* msa   = (const float*)d_in[0];
    const float* pairI = (const float*)d_in[1];
    const float* gamma = (const float*)d_in[4];
    const float* beta  = (const float*)d_in[5];
    const float* wl    = (const float*)d_in[6];
    const float* bl    = (const float*)d_in[7];
    const float* wr    = (const float*)d_in[8];
    const float* br    = (const float*)d_in[9];
    const float* wout  = (const float*)d_in[10];
    const float* bout  = (const float*)d_in[11];
    float* out = (float*)d_out;

    unsigned short* leftT  = (unsigned short*)d_ws;
    unsigned short* rightT = leftT + 256 * 32 * 128;
    unsigned short* w2     = rightT + 256 * 32 * 128;
    unsigned short* wTg    = w2 + 131072;

    k_prep<<<dim3(72), 256, 0, stream>>>(wout, wl, wr, w2, wTg);
    k_lnproj<<<dim3(256, 4), 256, 0, stream>>>(msa, gamma, beta, wTg, bl, br, leftT, rightT);
    k_outer<<<dim3(64, 64), 256, 0, stream>>>(leftT, rightT, w2, bout, pairI, out);
}